// Round 5
// baseline (2748.566 us; speedup 1.0000x reference)
//
#include <hip/hip_runtime.h>
#include <hip/hip_fp16.h>
#include <hip/hip_cooperative_groups.h>
#include <math.h>

namespace cg = cooperative_groups;

// Net_76854144794847: GSDN dense-graph diffusion GCN. fp32 in / fp32 out.
// dur model: ~640us fixed harness poison fills + compute. Compute floor:
// adj scan 41us (HBM) + L1 diffusion ~36us (L2 BW) + gemm/etc ~20us.
#define N_NODES 8192
#define F_IN    512
#define HID     128
#define NCLS    16
#define MAX_ELL 256
#define C_RES   0.5555555555555556f   // 1/(1+alpha), alpha=0.8
#define C_PROP  0.4444444444444445f   // alpha/(1+alpha)

__device__ __forceinline__ float4 ld_h4(const __half* p) {
    const uint2 u = *reinterpret_cast<const uint2*>(p);
    const __half2 h0 = *reinterpret_cast<const __half2*>(&u.x);
    const __half2 h1 = *reinterpret_cast<const __half2*>(&u.y);
    const float2 f0 = __half22float2(h0);
    const float2 f1 = __half22float2(h1);
    return make_float4(f0.x, f0.y, f1.x, f1.y);
}
__device__ __forceinline__ void st_h4(__half* p, float4 v) {
    __half2 h0 = __floats2half2_rn(v.x, v.y);
    __half2 h1 = __floats2half2_rn(v.z, v.w);
    uint2 u;
    u.x = *reinterpret_cast<unsigned int*>(&h0);
    u.y = *reinterpret_cast<unsigned int*>(&h1);
    *reinterpret_cast<uint2*>(p) = u;
}
__device__ __forceinline__ void add4(float4& a, const float4 b) {
    a.x += b.x; a.y += b.y; a.z += b.z; a.w += b.w;
}

// ---------------------------------------------------------------------------
// K1 (fused): blocks 0..255 = GEMM1 (h1 = x@W1, 32 rows/block); blocks
// 256..8447 = adjacency scan (1 row/block). GEMM blocks dispatch first and
// hide under the 268 MB HBM-bound scan.
// ---------------------------------------------------------------------------
__global__ __launch_bounds__(256) void scan_gemm_kernel(
    const float* __restrict__ adj, const float* __restrict__ x,
    const float* __restrict__ W1,
    int* __restrict__ ell, int* __restrict__ nnz,
    float* __restrict__ dinv, float* __restrict__ arow,
    float* __restrict__ h1)
{
    if (blockIdx.x < 256) {
        // ---- GEMM1: 32 rows x 128 cols per block, thread = 4x4 ----
        const int tx = threadIdx.x & 31;
        const int ty = threadIdx.x >> 5;
        const int c  = tx * 4;
        const int r0 = blockIdx.x * 32 + ty * 4;
        const float4* W4 = reinterpret_cast<const float4*>(W1);
        const float4* xr[4];
        #pragma unroll
        for (int i = 0; i < 4; ++i)
            xr[i] = reinterpret_cast<const float4*>(x + (size_t)(r0 + i) * F_IN);
        float4 acc[4] = {{0,0,0,0},{0,0,0,0},{0,0,0,0},{0,0,0,0}};
        #pragma unroll 2
        for (int kk = 0; kk < F_IN / 4; ++kk) {
            const int k = kk * 4;
            const float4 w0 = W4[(size_t)(k + 0) * 32 + tx];
            const float4 w1 = W4[(size_t)(k + 1) * 32 + tx];
            const float4 w2 = W4[(size_t)(k + 2) * 32 + tx];
            const float4 w3 = W4[(size_t)(k + 3) * 32 + tx];
            #pragma unroll
            for (int i = 0; i < 4; ++i) {
                const float4 xv = xr[i][kk];
                acc[i].x = fmaf(xv.x, w0.x, acc[i].x);
                acc[i].y = fmaf(xv.x, w0.y, acc[i].y);
                acc[i].z = fmaf(xv.x, w0.z, acc[i].z);
                acc[i].w = fmaf(xv.x, w0.w, acc[i].w);
                acc[i].x = fmaf(xv.y, w1.x, acc[i].x);
                acc[i].y = fmaf(xv.y, w1.y, acc[i].y);
                acc[i].z = fmaf(xv.y, w1.z, acc[i].z);
                acc[i].w = fmaf(xv.y, w1.w, acc[i].w);
                acc[i].x = fmaf(xv.z, w2.x, acc[i].x);
                acc[i].y = fmaf(xv.z, w2.y, acc[i].y);
                acc[i].z = fmaf(xv.z, w2.z, acc[i].z);
                acc[i].w = fmaf(xv.z, w2.w, acc[i].w);
                acc[i].x = fmaf(xv.w, w3.x, acc[i].x);
                acc[i].y = fmaf(xv.w, w3.y, acc[i].y);
                acc[i].z = fmaf(xv.w, w3.z, acc[i].z);
                acc[i].w = fmaf(xv.w, w3.w, acc[i].w);
            }
        }
        #pragma unroll
        for (int i = 0; i < 4; ++i)
            *reinterpret_cast<float4*>(h1 + (size_t)(r0 + i) * HID + c) = acc[i];
    } else {
        // ---- adjacency scan: row r -> ELL + dinv + arow ----
        const int r = blockIdx.x - 256;
        __shared__ int cnt;
        if (threadIdx.x == 0) cnt = 0;
        __syncthreads();
        const uint4* row4 = reinterpret_cast<const uint4*>(adj + (size_t)r * N_NODES);
        int* __restrict__ erow = ell + (size_t)r * MAX_ELL;
        for (int b = threadIdx.x; b < N_NODES / 4; b += blockDim.x) {
            const uint4 v = row4[b];
            const int base = b * 4;
            if (v.x) { int p = atomicAdd(&cnt, 1); if (p < MAX_ELL) erow[p] = base + 0; }
            if (v.y) { int p = atomicAdd(&cnt, 1); if (p < MAX_ELL) erow[p] = base + 1; }
            if (v.z) { int p = atomicAdd(&cnt, 1); if (p < MAX_ELL) erow[p] = base + 2; }
            if (v.w) { int p = atomicAdd(&cnt, 1); if (p < MAX_ELL) erow[p] = base + 3; }
        }
        __syncthreads();
        if (threadIdx.x == 0) {
            int c = cnt; if (c > MAX_ELL) c = MAX_ELL;
            nnz[r] = c;
            const float di = rsqrtf((float)cnt + 1.0f);
            dinv[r] = di;
            arow[r] = C_PROP * di * di;
        }
    }
}

// ---------------------------------------------------------------------------
// K2 (cooperative, 1024 blocks x 256): layer-1 end-to-end.
// Phase A: s0 = dinv*h1 (fp16), hb = cres*dinv*h1 (regs+mem).
// 7 diffusion steps in prescaled fp16 space; final: o1 = relu(...+b1).
// Thread = 1 row x 4 cols (32 lanes/row, 8 rows/block).
// ---------------------------------------------------------------------------
__global__ __launch_bounds__(256, 4) void layer1_coop_kernel(
    const float* __restrict__ h1, const float* __restrict__ dinv,
    const float* __restrict__ arow, const float* __restrict__ b1,
    const int* __restrict__ ell, const int* __restrict__ nnz,
    __half* __restrict__ sA, __half* __restrict__ sB,
    float* __restrict__ hb, float* __restrict__ o1)
{
    cg::grid_group grid = cg::this_grid();
    const int tx = threadIdx.x & 31;
    const int r  = blockIdx.x * 8 + (threadIdx.x >> 5);
    const int c  = tx * 4;
    const size_t o = (size_t)r * HID + c;

    // Phase A
    const float di = dinv[r];
    const float4 hv = *reinterpret_cast<const float4*>(h1 + o);
    float4 sv = make_float4(di * hv.x, di * hv.y, di * hv.z, di * hv.w);
    st_h4(sA + o, sv);
    const float4 hbv = make_float4(C_RES * sv.x, C_RES * sv.y,
                                   C_RES * sv.z, C_RES * sv.w);
    *reinterpret_cast<float4*>(hb + o) = hbv;

    const int nn = nnz[r];
    const int* __restrict__ erow = ell + (size_t)r * MAX_ELL;
    const float Ai = arow[r];

    __threadfence();
    grid.sync();

    const __half* in = sA;
    __half* out = sB;
    #pragma unroll 1
    for (int s = 0; s < 7; ++s) {
        float4 a0 = ld_h4(in + o);            // self term
        float4 a1 = {0.f, 0.f, 0.f, 0.f};
        int t = 0;
        for (; t + 2 <= nn; t += 2) {
            const int j0 = erow[t];
            const int j1 = erow[t + 1];
            const float4 g0 = ld_h4(in + (size_t)j0 * HID + c);
            const float4 g1 = ld_h4(in + (size_t)j1 * HID + c);
            add4(a0, g0);
            add4(a1, g1);
        }
        if (t < nn) add4(a0, ld_h4(in + (size_t)erow[t] * HID + c));
        add4(a0, a1);
        float4 sn = make_float4(fmaf(Ai, a0.x, hbv.x), fmaf(Ai, a0.y, hbv.y),
                                fmaf(Ai, a0.z, hbv.z), fmaf(Ai, a0.w, hbv.w));
        st_h4(out + o, sn);
        __half* tmp = out; out = const_cast<__half*>(in); in = tmp;
        __threadfence();
        grid.sync();
    }
    // in == sB (7 steps). Final: o1 = relu(cprop*di*G + cres*h1 + b1)
    {
        float4 a0 = ld_h4(in + o);
        float4 a1 = {0.f, 0.f, 0.f, 0.f};
        int t = 0;
        for (; t + 2 <= nn; t += 2) {
            const int j0 = erow[t];
            const int j1 = erow[t + 1];
            const float4 g0 = ld_h4(in + (size_t)j0 * HID + c);
            const float4 g1 = ld_h4(in + (size_t)j1 * HID + c);
            add4(a0, g0);
            add4(a1, g1);
        }
        if (t < nn) add4(a0, ld_h4(in + (size_t)erow[t] * HID + c));
        add4(a0, a1);
        const float pd = C_PROP * di;
        const float4 bv = *reinterpret_cast<const float4*>(b1 + c);
        float4 ov;
        ov.x = fmaxf(fmaf(pd, a0.x, C_RES * hv.x) + bv.x, 0.f);
        ov.y = fmaxf(fmaf(pd, a0.y, C_RES * hv.y) + bv.y, 0.f);
        ov.z = fmaxf(fmaf(pd, a0.z, C_RES * hv.z) + bv.z, 0.f);
        ov.w = fmaxf(fmaf(pd, a0.w, C_RES * hv.w) + bv.w, 0.f);
        *reinterpret_cast<float4*>(o1 + o) = ov;
    }
}

// ---------------------------------------------------------------------------
// K3 (cooperative, 256 blocks x 256): layer 2 end-to-end.
// Phase gemm: h2 = o1@W2 (+ s2 = dinv*h2, hb2 = cres*dinv*h2); 32 rows/block,
// 8 thr/row x 2 cols. Then 7 fp32 diffusion steps (tid<128: 32 rows x 4 lanes
// x float4) and final step fused with log_softmax (quad shfl reduce).
// ---------------------------------------------------------------------------
__global__ __launch_bounds__(256, 4) void layer2_coop_kernel(
    const float* __restrict__ o1, const float* __restrict__ W2,
    const float* __restrict__ dinv, const float* __restrict__ arow,
    const float* __restrict__ b2,
    const int* __restrict__ ell, const int* __restrict__ nnz,
    float* __restrict__ s2A, float* __restrict__ s2B,
    float* __restrict__ h2, float* __restrict__ hb2,
    float* __restrict__ out)
{
    cg::grid_group grid = cg::this_grid();

    // ---- phase gemm ----
    {
        const int r  = blockIdx.x * 32 + (threadIdx.x >> 3);
        const int c0 = (threadIdx.x & 7) * 2;
        const float* ir = o1 + (size_t)r * HID;
        float a0 = 0.f, a1 = 0.f;
        #pragma unroll 8
        for (int k = 0; k < HID; ++k) {
            const float iv = ir[k];
            a0 = fmaf(iv, W2[k * NCLS + c0], a0);
            a1 = fmaf(iv, W2[k * NCLS + c0 + 1], a1);
        }
        const float di = dinv[r];
        const size_t o = (size_t)r * NCLS + c0;
        h2[o]      = a0;      h2[o + 1]  = a1;
        s2A[o]     = di * a0; s2A[o + 1] = di * a1;
        hb2[o]     = C_RES * di * a0;
        hb2[o + 1] = C_RES * di * a1;
    }
    __threadfence();
    grid.sync();

    const bool active = (threadIdx.x < 128);
    const int l4 = threadIdx.x & 3;
    const int r  = blockIdx.x * 32 + (threadIdx.x >> 2);   // valid for active
    const int c  = l4 * 4;
    const size_t o = (size_t)r * NCLS + c;

    int nn = 0; const int* erow = nullptr;
    float Ai = 0.f; float4 hbv = {0,0,0,0};
    if (active) {
        nn = nnz[r];
        erow = ell + (size_t)r * MAX_ELL;
        Ai = arow[r];
        hbv = *reinterpret_cast<const float4*>(hb2 + o);
    }

    const float* in = s2A;
    float* outb = s2B;
    #pragma unroll 1
    for (int s = 0; s < 7; ++s) {
        if (active) {
            float4 a0 = *reinterpret_cast<const float4*>(in + o);
            float4 a1 = {0.f, 0.f, 0.f, 0.f};
            int t = 0;
            for (; t + 2 <= nn; t += 2) {
                const int j0 = erow[t];
                const int j1 = erow[t + 1];
                add4(a0, *reinterpret_cast<const float4*>(in + (size_t)j0 * NCLS + c));
                add4(a1, *reinterpret_cast<const float4*>(in + (size_t)j1 * NCLS + c));
            }
            if (t < nn)
                add4(a0, *reinterpret_cast<const float4*>(in + (size_t)erow[t] * NCLS + c));
            add4(a0, a1);
            float4 sn = make_float4(fmaf(Ai, a0.x, hbv.x), fmaf(Ai, a0.y, hbv.y),
                                    fmaf(Ai, a0.z, hbv.z), fmaf(Ai, a0.w, hbv.w));
            *reinterpret_cast<float4*>(outb + o) = sn;
        }
        float* tmp = outb; outb = const_cast<float*>(in); in = tmp;
        __threadfence();
        grid.sync();
    }
    // in == s2B. Final + log_softmax.
    if (active) {
        float4 a0 = *reinterpret_cast<const float4*>(in + o);
        float4 a1 = {0.f, 0.f, 0.f, 0.f};
        int t = 0;
        for (; t + 2 <= nn; t += 2) {
            const int j0 = erow[t];
            const int j1 = erow[t + 1];
            add4(a0, *reinterpret_cast<const float4*>(in + (size_t)j0 * NCLS + c));
            add4(a1, *reinterpret_cast<const float4*>(in + (size_t)j1 * NCLS + c));
        }
        if (t < nn)
            add4(a0, *reinterpret_cast<const float4*>(in + (size_t)erow[t] * NCLS + c));
        add4(a0, a1);
        const float pd = C_PROP * dinv[r];
        const float4 hv = *reinterpret_cast<const float4*>(h2 + o);
        const float4 bv = *reinterpret_cast<const float4*>(b2 + c);
        float4 ov;
        ov.x = fmaf(pd, a0.x, C_RES * hv.x) + bv.x;
        ov.y = fmaf(pd, a0.y, C_RES * hv.y) + bv.y;
        ov.z = fmaf(pd, a0.z, C_RES * hv.z) + bv.z;
        ov.w = fmaf(pd, a0.w, C_RES * hv.w) + bv.w;
        float mx = fmaxf(fmaxf(ov.x, ov.y), fmaxf(ov.z, ov.w));
        mx = fmaxf(mx, __shfl_xor(mx, 1));
        mx = fmaxf(mx, __shfl_xor(mx, 2));
        float s = __expf(ov.x - mx) + __expf(ov.y - mx) +
                  __expf(ov.z - mx) + __expf(ov.w - mx);
        s += __shfl_xor(s, 1);
        s += __shfl_xor(s, 2);
        const float lse = mx + __logf(s);
        *reinterpret_cast<float4*>(out + o) =
            make_float4(ov.x - lse, ov.y - lse, ov.z - lse, ov.w - lse);
    }
}

// ---------------------------------------------------------------------------
extern "C" void kernel_launch(void* const* d_in, const int* in_sizes, int n_in,
                              void* d_out, int out_size, void* d_ws, size_t ws_size,
                              hipStream_t stream)
{
    const float* x   = (const float*)d_in[0];
    const float* adj = (const float*)d_in[1];
    const float* W1  = (const float*)d_in[2];
    const float* b1  = (const float*)d_in[3];
    const float* W2  = (const float*)d_in[4];
    const float* b2  = (const float*)d_in[5];
    float* out = (float*)d_out;

    char* ws = (char*)d_ws;
    size_t off = 0;
    auto carve = [&](size_t bytes) -> void* {
        void* p = ws + off;
        off += (bytes + 255) & ~(size_t)255;
        return p;
    };
    int*    ell  = (int*)   carve((size_t)N_NODES * MAX_ELL * sizeof(int));
    int*    nnz  = (int*)   carve((size_t)N_NODES * sizeof(int));
    float*  dinv = (float*) carve((size_t)N_NODES * sizeof(float));
    float*  arow = (float*) carve((size_t)N_NODES * sizeof(float));
    float*  h1   = (float*) carve((size_t)N_NODES * HID * sizeof(float));
    float*  hb   = (float*) carve((size_t)N_NODES * HID * sizeof(float));
    __half* sA   = (__half*)carve((size_t)N_NODES * HID * sizeof(__half));
    __half* sB   = (__half*)carve((size_t)N_NODES * HID * sizeof(__half));
    float*  o1   = (float*) carve((size_t)N_NODES * HID * sizeof(float));
    float*  h2   = (float*) carve((size_t)N_NODES * NCLS * sizeof(float));
    float*  hb2  = (float*) carve((size_t)N_NODES * NCLS * sizeof(float));
    float*  s2A  = (float*) carve((size_t)N_NODES * NCLS * sizeof(float));
    float*  s2B  = (float*) carve((size_t)N_NODES * NCLS * sizeof(float));

    // K1: fused adjacency scan + GEMM1
    scan_gemm_kernel<<<8448, 256, 0, stream>>>(adj, x, W1, ell, nnz, dinv, arow, h1);

    // K2: cooperative layer-1 (prep + 7 steps + relu epilogue)
    {
        void* args[] = {(void*)&h1, (void*)&dinv, (void*)&arow, (void*)&b1,
                        (void*)&ell, (void*)&nnz, (void*)&sA, (void*)&sB,
                        (void*)&hb, (void*)&o1};
        hipLaunchCooperativeKernel((const void*)layer1_coop_kernel,
                                   dim3(1024), dim3(256), args, 0, stream);
    }

    // K3: cooperative layer-2 (gemm2 + 7 steps + final/lsm)
    {
        void* args[] = {(void*)&o1, (void*)&W2, (void*)&dinv, (void*)&arow,
                        (void*)&b2, (void*)&ell, (void*)&nnz, (void*)&s2A,
                        (void*)&s2B, (void*)&h2, (void*)&hb2, (void*)&out};
        hipLaunchCooperativeKernel((const void*)layer2_coop_kernel,
                                   dim3(256), dim3(256), args, 0, stream);
    }
    (void)in_sizes; (void)n_in; (void)out_size; (void)ws_size;
}

// Round 6
// 754.219 us; speedup vs baseline: 3.6443x; 3.6443x over previous
//
#include <hip/hip_runtime.h>
#include <hip/hip_fp16.h>
#include <math.h>

// Net_76854144794847: GSDN dense-graph diffusion GCN. fp32 in / fp32 out.
// dur model: ~640us fixed harness poison fills + ~120us compute.
// R5 lesson: cooperative grid.sync() costs ~200us/barrier on MI355X -> use
// per-step kernel launches (2us each) for inter-step global sync.
#define N_NODES 8192
#define F_IN    512
#define HID     128
#define NCLS    16
#define MAX_ELL 256
#define C_RES   0.5555555555555556f   // 1/(1+alpha), alpha=0.8
#define C_PROP  0.4444444444444445f   // alpha/(1+alpha)

__device__ __forceinline__ float4 ld_h4(const __half* p) {
    const uint2 u = *reinterpret_cast<const uint2*>(p);
    const __half2 h0 = *reinterpret_cast<const __half2*>(&u.x);
    const __half2 h1 = *reinterpret_cast<const __half2*>(&u.y);
    const float2 f0 = __half22float2(h0);
    const float2 f1 = __half22float2(h1);
    return make_float4(f0.x, f0.y, f1.x, f1.y);
}
__device__ __forceinline__ void st_h4(__half* p, float4 v) {
    __half2 h0 = __floats2half2_rn(v.x, v.y);
    __half2 h1 = __floats2half2_rn(v.z, v.w);
    uint2 u;
    u.x = *reinterpret_cast<unsigned int*>(&h0);
    u.y = *reinterpret_cast<unsigned int*>(&h1);
    *reinterpret_cast<uint2*>(p) = u;
}
__device__ __forceinline__ void add4(float4& a, const float4 b) {
    a.x += b.x; a.y += b.y; a.z += b.z; a.w += b.w;
}

// ---------------------------------------------------------------------------
// K1 (fused): blocks 0..255 = GEMM1 (h1 = x@W1, 32 rows/block, epilogue also
// writes s0 = dinv-less later; here just h1). Blocks 256..8447 = adjacency
// scan (1 row/block). GEMM blocks dispatch first, hide under the 268 MB
// HBM-bound scan. NOTE: GEMM epilogue cannot use dinv (scan not done) -- the
// s0/hb prep happens in the first diffusion kernel's PREP template arm.
// ---------------------------------------------------------------------------
__global__ __launch_bounds__(256) void scan_gemm_kernel(
    const float* __restrict__ adj, const float* __restrict__ x,
    const float* __restrict__ W1,
    int* __restrict__ ell, int* __restrict__ nnz,
    float* __restrict__ dinv, float* __restrict__ arow,
    float* __restrict__ h1)
{
    if (blockIdx.x < 256) {
        const int tx = threadIdx.x & 31;
        const int ty = threadIdx.x >> 5;
        const int c  = tx * 4;
        const int r0 = blockIdx.x * 32 + ty * 4;
        const float4* W4 = reinterpret_cast<const float4*>(W1);
        const float4* xr[4];
        #pragma unroll
        for (int i = 0; i < 4; ++i)
            xr[i] = reinterpret_cast<const float4*>(x + (size_t)(r0 + i) * F_IN);
        float4 acc[4] = {{0,0,0,0},{0,0,0,0},{0,0,0,0},{0,0,0,0}};
        #pragma unroll 2
        for (int kk = 0; kk < F_IN / 4; ++kk) {
            const int k = kk * 4;
            const float4 w0 = W4[(size_t)(k + 0) * 32 + tx];
            const float4 w1 = W4[(size_t)(k + 1) * 32 + tx];
            const float4 w2 = W4[(size_t)(k + 2) * 32 + tx];
            const float4 w3 = W4[(size_t)(k + 3) * 32 + tx];
            #pragma unroll
            for (int i = 0; i < 4; ++i) {
                const float4 xv = xr[i][kk];
                acc[i].x = fmaf(xv.x, w0.x, acc[i].x);
                acc[i].y = fmaf(xv.x, w0.y, acc[i].y);
                acc[i].z = fmaf(xv.x, w0.z, acc[i].z);
                acc[i].w = fmaf(xv.x, w0.w, acc[i].w);
                acc[i].x = fmaf(xv.y, w1.x, acc[i].x);
                acc[i].y = fmaf(xv.y, w1.y, acc[i].y);
                acc[i].z = fmaf(xv.y, w1.z, acc[i].z);
                acc[i].w = fmaf(xv.y, w1.w, acc[i].w);
                acc[i].x = fmaf(xv.z, w2.x, acc[i].x);
                acc[i].y = fmaf(xv.z, w2.y, acc[i].y);
                acc[i].z = fmaf(xv.z, w2.z, acc[i].z);
                acc[i].w = fmaf(xv.z, w2.w, acc[i].w);
                acc[i].x = fmaf(xv.w, w3.x, acc[i].x);
                acc[i].y = fmaf(xv.w, w3.y, acc[i].y);
                acc[i].z = fmaf(xv.w, w3.z, acc[i].z);
                acc[i].w = fmaf(xv.w, w3.w, acc[i].w);
            }
        }
        #pragma unroll
        for (int i = 0; i < 4; ++i)
            *reinterpret_cast<float4*>(h1 + (size_t)(r0 + i) * HID + c) = acc[i];
    } else {
        const int r = blockIdx.x - 256;
        __shared__ int cnt;
        if (threadIdx.x == 0) cnt = 0;
        __syncthreads();
        const uint4* row4 = reinterpret_cast<const uint4*>(adj + (size_t)r * N_NODES);
        int* __restrict__ erow = ell + (size_t)r * MAX_ELL;
        for (int b = threadIdx.x; b < N_NODES / 4; b += blockDim.x) {
            const uint4 v = row4[b];
            const int base = b * 4;
            if (v.x) { int p = atomicAdd(&cnt, 1); if (p < MAX_ELL) erow[p] = base + 0; }
            if (v.y) { int p = atomicAdd(&cnt, 1); if (p < MAX_ELL) erow[p] = base + 1; }
            if (v.z) { int p = atomicAdd(&cnt, 1); if (p < MAX_ELL) erow[p] = base + 2; }
            if (v.w) { int p = atomicAdd(&cnt, 1); if (p < MAX_ELL) erow[p] = base + 3; }
        }
        __syncthreads();
        if (threadIdx.x == 0) {
            int c = cnt; if (c > MAX_ELL) c = MAX_ELL;
            nnz[r] = c;
            const float di = rsqrtf((float)cnt + 1.0f);
            dinv[r] = di;
            arow[r] = C_PROP * di * di;
        }
    }
}

// ---------------------------------------------------------------------------
// K2-prep: s0 = dinv*h1 (fp16), hb = cres*dinv*h1 (fp32). Pure elementwise.
// ---------------------------------------------------------------------------
__global__ __launch_bounds__(256) void prep1_kernel(
    const float* __restrict__ h1, const float* __restrict__ dinv,
    __half* __restrict__ s0, float* __restrict__ hb)
{
    const int tx = threadIdx.x & 31;
    const int r  = blockIdx.x * 8 + (threadIdx.x >> 5);
    const int c  = tx * 4;
    const size_t o = (size_t)r * HID + c;
    const float di = dinv[r];
    const float4 hv = *reinterpret_cast<const float4*>(h1 + o);
    float4 sv = make_float4(di * hv.x, di * hv.y, di * hv.z, di * hv.w);
    st_h4(s0 + o, sv);
    *reinterpret_cast<float4*>(hb + o) =
        make_float4(C_RES * sv.x, C_RES * sv.y, C_RES * sv.z, C_RES * sv.w);
}

// ---------------------------------------------------------------------------
// K3: layer-1 diffusion step in prescaled fp16 space:
//    s'_ic = A_i * ( sum_{j in nbr(i)} s_jc + s_ic ) + hb_ic
// thread = 1 row x 4 cols; 32 lanes/row; 8 rows/block.
// ---------------------------------------------------------------------------
__global__ __launch_bounds__(256) void diffuse1_kernel(
    const __half* __restrict__ sin, const float* __restrict__ hb,
    __half* __restrict__ sout,
    const int* __restrict__ ell, const int* __restrict__ nnz,
    const float* __restrict__ arow)
{
    const int tx = threadIdx.x & 31;
    const int r  = blockIdx.x * 8 + (threadIdx.x >> 5);
    const int c  = tx * 4;
    const int nn = nnz[r];
    const int* __restrict__ erow = ell + (size_t)r * MAX_ELL;

    float4 a0 = ld_h4(sin + (size_t)r * HID + c);   // self term
    float4 a1 = {0.f, 0.f, 0.f, 0.f};
    int t = 0;
    for (; t + 2 <= nn; t += 2) {
        const int j0 = erow[t];
        const int j1 = erow[t + 1];
        const float4 g0 = ld_h4(sin + (size_t)j0 * HID + c);
        const float4 g1 = ld_h4(sin + (size_t)j1 * HID + c);
        add4(a0, g0);
        add4(a1, g1);
    }
    if (t < nn) add4(a0, ld_h4(sin + (size_t)erow[t] * HID + c));
    add4(a0, a1);

    const float Ai = arow[r];
    const float4 hv = *reinterpret_cast<const float4*>(hb + (size_t)r * HID + c);
    float4 s = make_float4(fmaf(Ai, a0.x, hv.x), fmaf(Ai, a0.y, hv.y),
                           fmaf(Ai, a0.z, hv.z), fmaf(Ai, a0.w, hv.w));
    st_h4(sout + (size_t)r * HID + c, s);
}

// ---------------------------------------------------------------------------
// K4: layer-1 final: o1 = relu(cprop*dinv_i*G + cres*h1 + b1)  (fp32 out)
// ---------------------------------------------------------------------------
__global__ __launch_bounds__(256) void final1_kernel(
    const __half* __restrict__ sin, const float* __restrict__ h1,
    const float* __restrict__ b1, float* __restrict__ o1,
    const int* __restrict__ ell, const int* __restrict__ nnz,
    const float* __restrict__ dinv)
{
    const int tx = threadIdx.x & 31;
    const int r  = blockIdx.x * 8 + (threadIdx.x >> 5);
    const int c  = tx * 4;
    const int nn = nnz[r];
    const int* __restrict__ erow = ell + (size_t)r * MAX_ELL;

    float4 a0 = ld_h4(sin + (size_t)r * HID + c);
    float4 a1 = {0.f, 0.f, 0.f, 0.f};
    int t = 0;
    for (; t + 2 <= nn; t += 2) {
        const int j0 = erow[t];
        const int j1 = erow[t + 1];
        const float4 g0 = ld_h4(sin + (size_t)j0 * HID + c);
        const float4 g1 = ld_h4(sin + (size_t)j1 * HID + c);
        add4(a0, g0);
        add4(a1, g1);
    }
    if (t < nn) add4(a0, ld_h4(sin + (size_t)erow[t] * HID + c));
    add4(a0, a1);

    const float pd = C_PROP * dinv[r];
    const float4 hv = *reinterpret_cast<const float4*>(h1 + (size_t)r * HID + c);
    const float4 bv = *reinterpret_cast<const float4*>(b1 + c);
    float4 o;
    o.x = fmaxf(fmaf(pd, a0.x, C_RES * hv.x) + bv.x, 0.f);
    o.y = fmaxf(fmaf(pd, a0.y, C_RES * hv.y) + bv.y, 0.f);
    o.z = fmaxf(fmaf(pd, a0.z, C_RES * hv.z) + bv.z, 0.f);
    o.w = fmaxf(fmaf(pd, a0.w, C_RES * hv.w) + bv.w, 0.f);
    *reinterpret_cast<float4*>(o1 + (size_t)r * HID + c) = o;
}

// ---------------------------------------------------------------------------
// K5: h2 = o1 @ W2; epilogue writes h2, s2 = dinv*h2, hb2 = cres*dinv*h2.
// ---------------------------------------------------------------------------
__global__ __launch_bounds__(256) void gemm_hw2_kernel(
    const float* __restrict__ o1, const float* __restrict__ W2,
    const float* __restrict__ dinv,
    float* __restrict__ h2, float* __restrict__ s2, float* __restrict__ hb2)
{
    const int c = threadIdx.x & (NCLS - 1);
    const int r = blockIdx.x * 16 + (threadIdx.x >> 4);
    const float* ir = o1 + (size_t)r * HID;
    float acc = 0.f;
    #pragma unroll 8
    for (int k = 0; k < HID; ++k)
        acc = fmaf(ir[k], W2[k * NCLS + c], acc);
    const float di = dinv[r];
    const size_t o = (size_t)r * NCLS + c;
    h2[o]  = acc;
    s2[o]  = di * acc;
    hb2[o] = C_RES * di * acc;
}

// ---------------------------------------------------------------------------
// K6: layer-2 diffusion step (fp32, 16 cols = 4 lanes x float4, 64 rows/blk)
// ---------------------------------------------------------------------------
__global__ __launch_bounds__(256) void diffuse2_kernel(
    const float* __restrict__ sin, const float* __restrict__ hb2,
    float* __restrict__ sout,
    const int* __restrict__ ell, const int* __restrict__ nnz,
    const float* __restrict__ arow)
{
    const int l4 = threadIdx.x & 3;
    const int r  = blockIdx.x * 64 + (threadIdx.x >> 2);
    const int c  = l4 * 4;
    const int nn = nnz[r];
    const int* __restrict__ erow = ell + (size_t)r * MAX_ELL;

    float4 a0 = *reinterpret_cast<const float4*>(sin + (size_t)r * NCLS + c);
    float4 a1 = {0.f, 0.f, 0.f, 0.f};
    int t = 0;
    for (; t + 2 <= nn; t += 2) {
        const int j0 = erow[t];
        const int j1 = erow[t + 1];
        add4(a0, *reinterpret_cast<const float4*>(sin + (size_t)j0 * NCLS + c));
        add4(a1, *reinterpret_cast<const float4*>(sin + (size_t)j1 * NCLS + c));
    }
    if (t < nn)
        add4(a0, *reinterpret_cast<const float4*>(sin + (size_t)erow[t] * NCLS + c));
    add4(a0, a1);

    const float Ai = arow[r];
    const float4 hv = *reinterpret_cast<const float4*>(hb2 + (size_t)r * NCLS + c);
    float4 s = make_float4(fmaf(Ai, a0.x, hv.x), fmaf(Ai, a0.y, hv.y),
                           fmaf(Ai, a0.z, hv.z), fmaf(Ai, a0.w, hv.w));
    *reinterpret_cast<float4*>(sout + (size_t)r * NCLS + c) = s;
}

// ---------------------------------------------------------------------------
// K7: layer-2 final fused with log_softmax (quad shfl reduce).
// ---------------------------------------------------------------------------
__global__ __launch_bounds__(256) void final2_lsm_kernel(
    const float* __restrict__ sin, const float* __restrict__ h2,
    const float* __restrict__ b2, float* __restrict__ out,
    const int* __restrict__ ell, const int* __restrict__ nnz,
    const float* __restrict__ dinv)
{
    const int l4 = threadIdx.x & 3;
    const int r  = blockIdx.x * 64 + (threadIdx.x >> 2);
    const int c  = l4 * 4;
    const int nn = nnz[r];
    const int* __restrict__ erow = ell + (size_t)r * MAX_ELL;

    float4 a0 = *reinterpret_cast<const float4*>(sin + (size_t)r * NCLS + c);
    float4 a1 = {0.f, 0.f, 0.f, 0.f};
    int t = 0;
    for (; t + 2 <= nn; t += 2) {
        const int j0 = erow[t];
        const int j1 = erow[t + 1];
        add4(a0, *reinterpret_cast<const float4*>(sin + (size_t)j0 * NCLS + c));
        add4(a1, *reinterpret_cast<const float4*>(sin + (size_t)j1 * NCLS + c));
    }
    if (t < nn)
        add4(a0, *reinterpret_cast<const float4*>(sin + (size_t)erow[t] * NCLS + c));
    add4(a0, a1);

    const float pd = C_PROP * dinv[r];
    const float4 hv = *reinterpret_cast<const float4*>(h2 + (size_t)r * NCLS + c);
    const float4 bv = *reinterpret_cast<const float4*>(b2 + c);
    float4 o;
    o.x = fmaf(pd, a0.x, C_RES * hv.x) + bv.x;
    o.y = fmaf(pd, a0.y, C_RES * hv.y) + bv.y;
    o.z = fmaf(pd, a0.z, C_RES * hv.z) + bv.z;
    o.w = fmaf(pd, a0.w, C_RES * hv.w) + bv.w;

    float mx = fmaxf(fmaxf(o.x, o.y), fmaxf(o.z, o.w));
    mx = fmaxf(mx, __shfl_xor(mx, 1));
    mx = fmaxf(mx, __shfl_xor(mx, 2));
    float s = __expf(o.x - mx) + __expf(o.y - mx) + __expf(o.z - mx) + __expf(o.w - mx);
    s += __shfl_xor(s, 1);
    s += __shfl_xor(s, 2);
    const float lse = mx + __logf(s);
    *reinterpret_cast<float4*>(out + (size_t)r * NCLS + c) =
        make_float4(o.x - lse, o.y - lse, o.z - lse, o.w - lse);
}

// ---------------------------------------------------------------------------
extern "C" void kernel_launch(void* const* d_in, const int* in_sizes, int n_in,
                              void* d_out, int out_size, void* d_ws, size_t ws_size,
                              hipStream_t stream)
{
    const float* x   = (const float*)d_in[0];
    const float* adj = (const float*)d_in[1];
    const float* W1  = (const float*)d_in[2];
    const float* b1  = (const float*)d_in[3];
    const float* W2  = (const float*)d_in[4];
    const float* b2  = (const float*)d_in[5];
    float* out = (float*)d_out;

    char* ws = (char*)d_ws;
    size_t off = 0;
    auto carve = [&](size_t bytes) -> void* {
        void* p = ws + off;
        off += (bytes + 255) & ~(size_t)255;
        return p;
    };
    int*    ell  = (int*)   carve((size_t)N_NODES * MAX_ELL * sizeof(int));
    int*    nnz  = (int*)   carve((size_t)N_NODES * sizeof(int));
    float*  dinv = (float*) carve((size_t)N_NODES * sizeof(float));
    float*  arow = (float*) carve((size_t)N_NODES * sizeof(float));
    float*  h1   = (float*) carve((size_t)N_NODES * HID * sizeof(float));
    float*  hb   = (float*) carve((size_t)N_NODES * HID * sizeof(float));
    __half* sA   = (__half*)carve((size_t)N_NODES * HID * sizeof(__half));
    __half* sB   = (__half*)carve((size_t)N_NODES * HID * sizeof(__half));
    float*  o1   = (float*) carve((size_t)N_NODES * HID * sizeof(float));
    float*  h2   = (float*) carve((size_t)N_NODES * NCLS * sizeof(float));
    float*  hb2  = (float*) carve((size_t)N_NODES * NCLS * sizeof(float));
    float*  s2A  = (float*) carve((size_t)N_NODES * NCLS * sizeof(float));
    float*  s2B  = (float*) carve((size_t)N_NODES * NCLS * sizeof(float));

    // K1: fused adjacency scan + GEMM1 (GEMM hides under HBM-bound scan)
    scan_gemm_kernel<<<8448, 256, 0, stream>>>(adj, x, W1, ell, nnz, dinv, arow, h1);

    // K2: prep s0/hb (needs dinv -> after scan)
    prep1_kernel<<<N_NODES / 8, 256, 0, stream>>>(h1, dinv, sA, hb);

    // layer-1: 7 fp16 diffusion steps + final relu step
    {
        const __half* cur = sA;
        __half* bufs[2] = {sB, sA};
        for (int s = 0; s < 7; ++s) {
            __half* dst = bufs[s & 1];
            diffuse1_kernel<<<N_NODES / 8, 256, 0, stream>>>(cur, hb, dst, ell, nnz, arow);
            cur = dst;
        }
        final1_kernel<<<N_NODES / 8, 256, 0, stream>>>(cur, h1, b1, o1, ell, nnz, dinv);
    }

    // layer-2: gemm + 7 fp32 diffusion steps + final/lsm
    gemm_hw2_kernel<<<N_NODES / 16, 256, 0, stream>>>(o1, W2, dinv, h2, s2A, hb2);
    {
        const float* cur = s2A;
        float* bufs[2] = {s2B, s2A};
        for (int s = 0; s < 7; ++s) {
            float* dst = bufs[s & 1];
            diffuse2_kernel<<<N_NODES / 64, 256, 0, stream>>>(cur, hb2, dst, ell, nnz, arow);
            cur = dst;
        }
        final2_lsm_kernel<<<N_NODES / 64, 256, 0, stream>>>(cur, h2, b2, out, ell, nnz, dinv);
    }
    (void)in_sizes; (void)n_in; (void)out_size; (void)ws_size;
}

// Round 7
// 699.367 us; speedup vs baseline: 3.9301x; 1.0784x over previous
//
#include <hip/hip_runtime.h>
#include <hip/hip_fp16.h>
#include <math.h>

// Net_76854144794847: GSDN dense-graph diffusion GCN. fp32 in / fp32 out.
// dur model: ~640us fixed harness poison fills + ~110us compute.
// R5 lesson: coop grid.sync() ~200us/barrier on MI355X -> per-step launches.
#define N_NODES 8192
#define F_IN    512
#define HID     128
#define NCLS    16
#define MAX_ELL 256
#define C_RES   0.5555555555555556f   // 1/(1+alpha), alpha=0.8
#define C_PROP  0.4444444444444445f   // alpha/(1+alpha)

__device__ __forceinline__ float4 ld_h4(const __half* p) {
    const uint2 u = *reinterpret_cast<const uint2*>(p);
    const __half2 h0 = *reinterpret_cast<const __half2*>(&u.x);
    const __half2 h1 = *reinterpret_cast<const __half2*>(&u.y);
    const float2 f0 = __half22float2(h0);
    const float2 f1 = __half22float2(h1);
    return make_float4(f0.x, f0.y, f1.x, f1.y);
}
__device__ __forceinline__ void st_h4(__half* p, float4 v) {
    __half2 h0 = __floats2half2_rn(v.x, v.y);
    __half2 h1 = __floats2half2_rn(v.z, v.w);
    uint2 u;
    u.x = *reinterpret_cast<unsigned int*>(&h0);
    u.y = *reinterpret_cast<unsigned int*>(&h1);
    *reinterpret_cast<uint2*>(p) = u;
}
__device__ __forceinline__ void add4(float4& a, const float4 b) {
    a.x += b.x; a.y += b.y; a.z += b.z; a.w += b.w;
}

// ---------------------------------------------------------------------------
// K1 (fused): blocks 0..255 = GEMM1 (h1 = x@W1); blocks 256..8447 = adjacency
// scan (1 row/block). GEMM blocks dispatch first, hide under the 268 MB
// HBM-bound scan (~41us floor).
// ---------------------------------------------------------------------------
__global__ __launch_bounds__(256) void scan_gemm_kernel(
    const float* __restrict__ adj, const float* __restrict__ x,
    const float* __restrict__ W1,
    int* __restrict__ ell, int* __restrict__ nnz,
    float* __restrict__ dinv, float* __restrict__ arow,
    float* __restrict__ h1)
{
    if (blockIdx.x < 256) {
        const int tx = threadIdx.x & 31;
        const int ty = threadIdx.x >> 5;
        const int c  = tx * 4;
        const int r0 = blockIdx.x * 32 + ty * 4;
        const float4* W4 = reinterpret_cast<const float4*>(W1);
        const float4* xr[4];
        #pragma unroll
        for (int i = 0; i < 4; ++i)
            xr[i] = reinterpret_cast<const float4*>(x + (size_t)(r0 + i) * F_IN);
        float4 acc[4] = {{0,0,0,0},{0,0,0,0},{0,0,0,0},{0,0,0,0}};
        #pragma unroll 2
        for (int kk = 0; kk < F_IN / 4; ++kk) {
            const int k = kk * 4;
            const float4 w0 = W4[(size_t)(k + 0) * 32 + tx];
            const float4 w1 = W4[(size_t)(k + 1) * 32 + tx];
            const float4 w2 = W4[(size_t)(k + 2) * 32 + tx];
            const float4 w3 = W4[(size_t)(k + 3) * 32 + tx];
            #pragma unroll
            for (int i = 0; i < 4; ++i) {
                const float4 xv = xr[i][kk];
                acc[i].x = fmaf(xv.x, w0.x, acc[i].x);
                acc[i].y = fmaf(xv.x, w0.y, acc[i].y);
                acc[i].z = fmaf(xv.x, w0.z, acc[i].z);
                acc[i].w = fmaf(xv.x, w0.w, acc[i].w);
                acc[i].x = fmaf(xv.y, w1.x, acc[i].x);
                acc[i].y = fmaf(xv.y, w1.y, acc[i].y);
                acc[i].z = fmaf(xv.y, w1.z, acc[i].z);
                acc[i].w = fmaf(xv.y, w1.w, acc[i].w);
                acc[i].x = fmaf(xv.z, w2.x, acc[i].x);
                acc[i].y = fmaf(xv.z, w2.y, acc[i].y);
                acc[i].z = fmaf(xv.z, w2.z, acc[i].z);
                acc[i].w = fmaf(xv.z, w2.w, acc[i].w);
                acc[i].x = fmaf(xv.w, w3.x, acc[i].x);
                acc[i].y = fmaf(xv.w, w3.y, acc[i].y);
                acc[i].z = fmaf(xv.w, w3.z, acc[i].z);
                acc[i].w = fmaf(xv.w, w3.w, acc[i].w);
            }
        }
        #pragma unroll
        for (int i = 0; i < 4; ++i)
            *reinterpret_cast<float4*>(h1 + (size_t)(r0 + i) * HID + c) = acc[i];
    } else {
        const int r = blockIdx.x - 256;
        __shared__ int cnt;
        if (threadIdx.x == 0) cnt = 0;
        __syncthreads();
        const uint4* row4 = reinterpret_cast<const uint4*>(adj + (size_t)r * N_NODES);
        int* __restrict__ erow = ell + (size_t)r * MAX_ELL;
        for (int b = threadIdx.x; b < N_NODES / 4; b += blockDim.x) {
            const uint4 v = row4[b];
            const int base = b * 4;
            if (v.x) { int p = atomicAdd(&cnt, 1); if (p < MAX_ELL) erow[p] = base + 0; }
            if (v.y) { int p = atomicAdd(&cnt, 1); if (p < MAX_ELL) erow[p] = base + 1; }
            if (v.z) { int p = atomicAdd(&cnt, 1); if (p < MAX_ELL) erow[p] = base + 2; }
            if (v.w) { int p = atomicAdd(&cnt, 1); if (p < MAX_ELL) erow[p] = base + 3; }
        }
        __syncthreads();
        if (threadIdx.x == 0) {
            int c = cnt; if (c > MAX_ELL) c = MAX_ELL;
            nnz[r] = c;
            const float di = rsqrtf((float)cnt + 1.0f);
            dinv[r] = di;
            arow[r] = C_PROP * di * di;
        }
    }
}

// ---------------------------------------------------------------------------
// K2: s0 = dinv*h1 (fp16), hb = cres*dinv*h1 (fp32). Elementwise.
// ---------------------------------------------------------------------------
__global__ __launch_bounds__(256) void prep1_kernel(
    const float* __restrict__ h1, const float* __restrict__ dinv,
    __half* __restrict__ s0, float* __restrict__ hb)
{
    const int tx = threadIdx.x & 31;
    const int r  = blockIdx.x * 8 + (threadIdx.x >> 5);
    const int c  = tx * 4;
    const size_t o = (size_t)r * HID + c;
    const float di = dinv[r];
    const float4 hv = *reinterpret_cast<const float4*>(h1 + o);
    float4 sv = make_float4(di * hv.x, di * hv.y, di * hv.z, di * hv.w);
    st_h4(s0 + o, sv);
    *reinterpret_cast<float4*>(hb + o) =
        make_float4(C_RES * sv.x, C_RES * sv.y, C_RES * sv.z, C_RES * sv.w);
}

// ---------------------------------------------------------------------------
// K3: layer-1 diffusion step, prescaled fp16 space, 4-way unrolled gathers.
// thread = 1 row x 4 cols; 32 lanes/row; 8 rows/block.
// ---------------------------------------------------------------------------
__global__ __launch_bounds__(256) void diffuse1_kernel(
    const __half* __restrict__ sin, const float* __restrict__ hb,
    __half* __restrict__ sout,
    const int* __restrict__ ell, const int* __restrict__ nnz,
    const float* __restrict__ arow)
{
    const int tx = threadIdx.x & 31;
    const int r  = blockIdx.x * 8 + (threadIdx.x >> 5);
    const int c  = tx * 4;
    const int nn = nnz[r];
    const int* __restrict__ erow = ell + (size_t)r * MAX_ELL;

    const float4 hv = *reinterpret_cast<const float4*>(hb + (size_t)r * HID + c);
    float4 a0 = ld_h4(sin + (size_t)r * HID + c);   // self term
    float4 a1 = {0,0,0,0}, a2 = {0,0,0,0}, a3 = {0,0,0,0};
    int t = 0;
    for (; t + 4 <= nn; t += 4) {
        const int j0 = erow[t + 0];
        const int j1 = erow[t + 1];
        const int j2 = erow[t + 2];
        const int j3 = erow[t + 3];
        const float4 g0 = ld_h4(sin + (size_t)j0 * HID + c);
        const float4 g1 = ld_h4(sin + (size_t)j1 * HID + c);
        const float4 g2 = ld_h4(sin + (size_t)j2 * HID + c);
        const float4 g3 = ld_h4(sin + (size_t)j3 * HID + c);
        add4(a0, g0); add4(a1, g1); add4(a2, g2); add4(a3, g3);
    }
    for (; t < nn; ++t) add4(a1, ld_h4(sin + (size_t)erow[t] * HID + c));
    add4(a0, a1); add4(a2, a3); add4(a0, a2);

    const float Ai = arow[r];
    float4 s = make_float4(fmaf(Ai, a0.x, hv.x), fmaf(Ai, a0.y, hv.y),
                           fmaf(Ai, a0.z, hv.z), fmaf(Ai, a0.w, hv.w));
    st_h4(sout + (size_t)r * HID + c, s);
}

// ---------------------------------------------------------------------------
// K4 (merged final1 + gemm2): per row r,
//   o1_c = relu(cprop*dinv_r*G_c + cres*h1_c + b1_c)     (kept in regs)
//   h2[r][:] = o1_row @ W2  via per-lane partials + 5-step shfl_xor butterfly
//   (32 lanes/row; masks 1..16 stay within each 32-lane half of the wave).
// Epilogue lanes 0..15 write h2, s2 = dinv*h2, hb2 = cres*dinv*h2.
// Removes the o1 buffer entirely (8 MB L2 round-trip) and one launch.
// ---------------------------------------------------------------------------
__global__ __launch_bounds__(256) void final1_gemm_kernel(
    const __half* __restrict__ sin, const float* __restrict__ h1,
    const float* __restrict__ b1, const float* __restrict__ W2,
    const int* __restrict__ ell, const int* __restrict__ nnz,
    const float* __restrict__ dinv,
    float* __restrict__ h2, float* __restrict__ s2, float* __restrict__ hb2)
{
    const int tx = threadIdx.x & 31;
    const int r  = blockIdx.x * 8 + (threadIdx.x >> 5);
    const int c  = tx * 4;
    const int nn = nnz[r];
    const int* __restrict__ erow = ell + (size_t)r * MAX_ELL;

    float4 a0 = ld_h4(sin + (size_t)r * HID + c);
    float4 a1 = {0,0,0,0}, a2 = {0,0,0,0}, a3 = {0,0,0,0};
    int t = 0;
    for (; t + 4 <= nn; t += 4) {
        const int j0 = erow[t + 0];
        const int j1 = erow[t + 1];
        const int j2 = erow[t + 2];
        const int j3 = erow[t + 3];
        const float4 g0 = ld_h4(sin + (size_t)j0 * HID + c);
        const float4 g1 = ld_h4(sin + (size_t)j1 * HID + c);
        const float4 g2 = ld_h4(sin + (size_t)j2 * HID + c);
        const float4 g3 = ld_h4(sin + (size_t)j3 * HID + c);
        add4(a0, g0); add4(a1, g1); add4(a2, g2); add4(a3, g3);
    }
    for (; t < nn; ++t) add4(a1, ld_h4(sin + (size_t)erow[t] * HID + c));
    add4(a0, a1); add4(a2, a3); add4(a0, a2);

    const float di = dinv[r];
    const float pd = C_PROP * di;
    const float4 hv = *reinterpret_cast<const float4*>(h1 + (size_t)r * HID + c);
    const float4 bv = *reinterpret_cast<const float4*>(b1 + c);
    float ov[4];
    ov[0] = fmaxf(fmaf(pd, a0.x, C_RES * hv.x) + bv.x, 0.f);
    ov[1] = fmaxf(fmaf(pd, a0.y, C_RES * hv.y) + bv.y, 0.f);
    ov[2] = fmaxf(fmaf(pd, a0.z, C_RES * hv.z) + bv.z, 0.f);
    ov[3] = fmaxf(fmaf(pd, a0.w, C_RES * hv.w) + bv.w, 0.f);

    // per-lane partial dot products over this lane's 4 k-indices
    float p[NCLS];
    #pragma unroll
    for (int cc = 0; cc < NCLS; ++cc) p[cc] = 0.f;
    #pragma unroll
    for (int i = 0; i < 4; ++i) {
        const float* w = W2 + (size_t)(c + i) * NCLS;
        const float v = ov[i];
        #pragma unroll
        for (int cc = 0; cc < NCLS; ++cc) p[cc] = fmaf(v, w[cc], p[cc]);
    }
    // butterfly sum across the 32 lanes of this row group
    #pragma unroll
    for (int m = 1; m <= 16; m <<= 1) {
        #pragma unroll
        for (int cc = 0; cc < NCLS; ++cc) p[cc] += __shfl_xor(p[cc], m);
    }
    if (tx < NCLS) {
        const float v = p[tx];
        const size_t o = (size_t)r * NCLS + tx;
        h2[o]  = v;
        s2[o]  = di * v;
        hb2[o] = C_RES * di * v;
    }
}

// ---------------------------------------------------------------------------
// K5: layer-2 diffusion step (fp32, 16 cols = 4 lanes x float4, 64 rows/blk)
// ---------------------------------------------------------------------------
__global__ __launch_bounds__(256) void diffuse2_kernel(
    const float* __restrict__ sin, const float* __restrict__ hb2,
    float* __restrict__ sout,
    const int* __restrict__ ell, const int* __restrict__ nnz,
    const float* __restrict__ arow)
{
    const int l4 = threadIdx.x & 3;
    const int r  = blockIdx.x * 64 + (threadIdx.x >> 2);
    const int c  = l4 * 4;
    const int nn = nnz[r];
    const int* __restrict__ erow = ell + (size_t)r * MAX_ELL;

    float4 a0 = *reinterpret_cast<const float4*>(sin + (size_t)r * NCLS + c);
    float4 a1 = {0.f, 0.f, 0.f, 0.f};
    int t = 0;
    for (; t + 2 <= nn; t += 2) {
        const int j0 = erow[t];
        const int j1 = erow[t + 1];
        add4(a0, *reinterpret_cast<const float4*>(sin + (size_t)j0 * NCLS + c));
        add4(a1, *reinterpret_cast<const float4*>(sin + (size_t)j1 * NCLS + c));
    }
    if (t < nn)
        add4(a0, *reinterpret_cast<const float4*>(sin + (size_t)erow[t] * NCLS + c));
    add4(a0, a1);

    const float Ai = arow[r];
    const float4 hv = *reinterpret_cast<const float4*>(hb2 + (size_t)r * NCLS + c);
    float4 s = make_float4(fmaf(Ai, a0.x, hv.x), fmaf(Ai, a0.y, hv.y),
                           fmaf(Ai, a0.z, hv.z), fmaf(Ai, a0.w, hv.w));
    *reinterpret_cast<float4*>(sout + (size_t)r * NCLS + c) = s;
}

// ---------------------------------------------------------------------------
// K6: layer-2 final fused with log_softmax (quad shfl reduce).
// ---------------------------------------------------------------------------
__global__ __launch_bounds__(256) void final2_lsm_kernel(
    const float* __restrict__ sin, const float* __restrict__ h2,
    const float* __restrict__ b2, float* __restrict__ out,
    const int* __restrict__ ell, const int* __restrict__ nnz,
    const float* __restrict__ dinv)
{
    const int l4 = threadIdx.x & 3;
    const int r  = blockIdx.x * 64 + (threadIdx.x >> 2);
    const int c  = l4 * 4;
    const int nn = nnz[r];
    const int* __restrict__ erow = ell + (size_t)r * MAX_ELL;

    float4 a0 = *reinterpret_cast<const float4*>(sin + (size_t)r * NCLS + c);
    float4 a1 = {0.f, 0.f, 0.f, 0.f};
    int t = 0;
    for (; t + 2 <= nn; t += 2) {
        const int j0 = erow[t];
        const int j1 = erow[t + 1];
        add4(a0, *reinterpret_cast<const float4*>(sin + (size_t)j0 * NCLS + c));
        add4(a1, *reinterpret_cast<const float4*>(sin + (size_t)j1 * NCLS + c));
    }
    if (t < nn)
        add4(a0, *reinterpret_cast<const float4*>(sin + (size_t)erow[t] * NCLS + c));
    add4(a0, a1);

    const float pd = C_PROP * dinv[r];
    const float4 hv = *reinterpret_cast<const float4*>(h2 + (size_t)r * NCLS + c);
    const float4 bv = *reinterpret_cast<const float4*>(b2 + c);
    float4 o;
    o.x = fmaf(pd, a0.x, C_RES * hv.x) + bv.x;
    o.y = fmaf(pd, a0.y, C_RES * hv.y) + bv.y;
    o.z = fmaf(pd, a0.z, C_RES * hv.z) + bv.z;
    o.w = fmaf(pd, a0.w, C_RES * hv.w) + bv.w;

    float mx = fmaxf(fmaxf(o.x, o.y), fmaxf(o.z, o.w));
    mx = fmaxf(mx, __shfl_xor(mx, 1));
    mx = fmaxf(mx, __shfl_xor(mx, 2));
    float s = __expf(o.x - mx) + __expf(o.y - mx) + __expf(o.z - mx) + __expf(o.w - mx);
    s += __shfl_xor(s, 1);
    s += __shfl_xor(s, 2);
    const float lse = mx + __logf(s);
    *reinterpret_cast<float4*>(out + (size_t)r * NCLS + c) =
        make_float4(o.x - lse, o.y - lse, o.z - lse, o.w - lse);
}

// ---------------------------------------------------------------------------
extern "C" void kernel_launch(void* const* d_in, const int* in_sizes, int n_in,
                              void* d_out, int out_size, void* d_ws, size_t ws_size,
                              hipStream_t stream)
{
    const float* x   = (const float*)d_in[0];
    const float* adj = (const float*)d_in[1];
    const float* W1  = (const float*)d_in[2];
    const float* b1  = (const float*)d_in[3];
    const float* W2  = (const float*)d_in[4];
    const float* b2  = (const float*)d_in[5];
    float* out = (float*)d_out;

    char* ws = (char*)d_ws;
    size_t off = 0;
    auto carve = [&](size_t bytes) -> void* {
        void* p = ws + off;
        off += (bytes + 255) & ~(size_t)255;
        return p;
    };
    int*    ell  = (int*)   carve((size_t)N_NODES * MAX_ELL * sizeof(int));
    int*    nnz  = (int*)   carve((size_t)N_NODES * sizeof(int));
    float*  dinv = (float*) carve((size_t)N_NODES * sizeof(float));
    float*  arow = (float*) carve((size_t)N_NODES * sizeof(float));
    float*  h1   = (float*) carve((size_t)N_NODES * HID * sizeof(float));
    float*  hb   = (float*) carve((size_t)N_NODES * HID * sizeof(float));
    __half* sA   = (__half*)carve((size_t)N_NODES * HID * sizeof(__half));
    __half* sB   = (__half*)carve((size_t)N_NODES * HID * sizeof(__half));
    float*  h2   = (float*) carve((size_t)N_NODES * NCLS * sizeof(float));
    float*  hb2  = (float*) carve((size_t)N_NODES * NCLS * sizeof(float));
    float*  s2A  = (float*) carve((size_t)N_NODES * NCLS * sizeof(float));
    float*  s2B  = (float*) carve((size_t)N_NODES * NCLS * sizeof(float));

    // K1: fused adjacency scan + GEMM1 (GEMM hides under HBM-bound scan)
    scan_gemm_kernel<<<8448, 256, 0, stream>>>(adj, x, W1, ell, nnz, dinv, arow, h1);

    // K2: prep s0/hb (needs dinv -> after scan)
    prep1_kernel<<<N_NODES / 8, 256, 0, stream>>>(h1, dinv, sA, hb);

    // layer-1: 7 fp16 diffusion steps, then merged final+gemm2
    {
        const __half* cur = sA;
        __half* bufs[2] = {sB, sA};
        for (int s = 0; s < 7; ++s) {
            __half* dst = bufs[s & 1];
            diffuse1_kernel<<<N_NODES / 8, 256, 0, stream>>>(cur, hb, dst, ell, nnz, arow);
            cur = dst;
        }
        final1_gemm_kernel<<<N_NODES / 8, 256, 0, stream>>>(
            cur, h1, b1, W2, ell, nnz, dinv, h2, s2A, hb2);
    }

    // layer-2: 7 fp32 diffusion steps + final/lsm
    {
        const float* cur = s2A;
        float* bufs[2] = {s2B, s2A};
        for (int s = 0; s < 7; ++s) {
            float* dst = bufs[s & 1];
            diffuse2_kernel<<<N_NODES / 64, 256, 0, stream>>>(cur, hb2, dst, ell, nnz, arow);
            cur = dst;
        }
        final2_lsm_kernel<<<N_NODES / 64, 256, 0, stream>>>(cur, h2, b2, out, ell, nnz, dinv);
    }
    (void)in_sizes; (void)n_in; (void)out_size; (void)ws_size;
}